// Round 2
// baseline (401.776 us; speedup 1.0000x reference)
//
#include <hip/hip_runtime.h>
#include <stdint.h>

typedef __attribute__((ext_vector_type(8))) short short8;
typedef __attribute__((ext_vector_type(4))) float f32x4;

static constexpr int D  = 1024;
static constexpr int H  = 16;
static constexpr int L  = 4096;
static constexpr int NB = 4;
static constexpr int M  = NB * L;      // 16384 rows
static constexpr int NP = 3 * H * 64;  // 3072 param cols

__device__ __forceinline__ float bf2f(unsigned short u) {
    unsigned int v = ((unsigned int)u) << 16;
    return __builtin_bit_cast(float, v);
}
__device__ __forceinline__ unsigned short f2bf(float f) {
    unsigned int x = __builtin_bit_cast(unsigned int, f);
    x += 0x7fffu + ((x >> 16) & 1u);
    return (unsigned short)(x >> 16);
}
__device__ __forceinline__ void async_lds16(void* lds, const void* g) {
    __builtin_amdgcn_global_load_lds(
        (const __attribute__((address_space(1))) unsigned int*)g,
        (__attribute__((address_space(3))) unsigned int*)lds,
        16, 0, 0);
}

// ---------------- weight fp32 -> bf16 ----------------
__global__ __launch_bounds__(256) void cvt_bf16_kernel(const float* __restrict__ src,
                                                       unsigned short* __restrict__ dst, int n4) {
    const int i = (blockIdx.x * 256 + threadIdx.x);
    if (i < n4) {
        const float4 v = reinterpret_cast<const float4*>(src)[i];
        ushort4 o;
        o.x = f2bf(v.x); o.y = f2bf(v.y); o.z = f2bf(v.z); o.w = f2bf(v.w);
        reinterpret_cast<ushort4*>(dst)[i] = o;
    }
}

// ---------------- zero fill (uint4) ----------------
__global__ __launch_bounds__(256) void zfill_kernel(uint4* __restrict__ p) {
    p[(size_t)blockIdx.x * 256 + threadIdx.x] = uint4{0u, 0u, 0u, 0u};
}

// ---------------- RMSNorm (fp32 in -> bf16 out) ----------------
__global__ __launch_bounds__(256) void rmsnorm_kernel(const float* __restrict__ x,
                                                      const float* __restrict__ w,
                                                      unsigned short* __restrict__ xn) {
    const int row = blockIdx.x;
    const int t = threadIdx.x;
    const float4 v = *reinterpret_cast<const float4*>(x + (size_t)row * D + t * 4);
    float s = v.x * v.x + v.y * v.y + v.z * v.z + v.w * v.w;
    #pragma unroll
    for (int o = 32; o > 0; o >>= 1) s += __shfl_down(s, o, 64);
    __shared__ float red[4];
    if ((t & 63) == 0) red[t >> 6] = s;
    __syncthreads();
    const float tot = red[0] + red[1] + red[2] + red[3];
    const float rinv = 1.0f / sqrtf(tot * (1.0f / D) + 1e-6f);
    const float4 wv = *reinterpret_cast<const float4*>(w + t * 4);
    ushort4 o;
    o.x = f2bf(wv.x * v.x * rinv);
    o.y = f2bf(wv.y * v.y * rinv);
    o.z = f2bf(wv.z * v.z * rinv);
    o.w = f2bf(wv.w * v.w * rinv);
    *reinterpret_cast<ushort4*>(xn + (size_t)row * D + t * 4) = o;
}

// ---------------- depthwise causal conv (K=4) + SiLU (bf16 -> bf16) --------
__global__ __launch_bounds__(256) void conv_silu_kernel(const unsigned short* __restrict__ xn,
                                                        const float* __restrict__ cw,
                                                        const float* __restrict__ cb,
                                                        unsigned short* __restrict__ xc) {
    const int row = blockIdx.x;          // b*L + l
    const int l = row & (L - 1);
    const int d0 = threadIdx.x * 4;
    float a[4];
    float wv[4][4];
    #pragma unroll
    for (int dd = 0; dd < 4; ++dd) {
        a[dd] = cb[d0 + dd];
        const float4 wr = *reinterpret_cast<const float4*>(cw + (size_t)(d0 + dd) * 4);
        wv[dd][0] = wr.x; wv[dd][1] = wr.y; wv[dd][2] = wr.z; wv[dd][3] = wr.w;
    }
    #pragma unroll
    for (int k = 0; k < 4; ++k) {
        if (l - 3 + k >= 0) {
            const ushort4 v = *reinterpret_cast<const ushort4*>(xn + (size_t)(row - 3 + k) * D + d0);
            a[0] += wv[0][k] * bf2f(v.x);
            a[1] += wv[1][k] * bf2f(v.y);
            a[2] += wv[2][k] * bf2f(v.z);
            a[3] += wv[3][k] * bf2f(v.w);
        }
    }
    ushort4 o;
    o.x = f2bf(a[0] / (1.0f + expf(-a[0])));
    o.y = f2bf(a[1] / (1.0f + expf(-a[1])));
    o.z = f2bf(a[2] / (1.0f + expf(-a[2])));
    o.w = f2bf(a[3] / (1.0f + expf(-a[3])));
    *reinterpret_cast<ushort4*>(xc + (size_t)row * D + d0) = o;
}

// ---------------- bf16 MFMA GEMM: out[m,n] = sum_k A[m,k]*W[n,k] + epilogue ----
// EPI 0: gate = sigmoid(v + bias) -> bf16
// EPI 1: params: v += bias; sigmoid on delta cols -> bf16
// EPI 2: y = v + bias + xres -> fp32
template <int EPI>
__global__ __launch_bounds__(256) void gemm_bt_kernel(
    const unsigned short* __restrict__ A,   // M x 1024 bf16
    const unsigned short* __restrict__ W,   // N x 1024 bf16
    const float* __restrict__ bias,         // N
    const float* __restrict__ xres,         // M x N (EPI==2)
    float* __restrict__ outf,
    unsigned short* __restrict__ outh,
    const int N) {
    constexpr int K = 1024;
    constexpr int BK = 32;
    __shared__ alignas(16) unsigned short As[128 * BK];
    __shared__ alignas(16) unsigned short Bs[128 * BK];
    const int tid = threadIdx.x;
    const int wave = tid >> 6;
    const int lane = tid & 63;
    const int nbn = N >> 7;
    const int bm = (blockIdx.x / nbn) << 7;
    const int bn = (blockIdx.x % nbn) << 7;
    const int wr = wave >> 1, wc = wave & 1;
    const int lr = lane & 15, kg = lane >> 4;

    f32x4 zero = {0.f, 0.f, 0.f, 0.f};
    f32x4 acc[4][4];
    #pragma unroll
    for (int i = 0; i < 4; ++i)
        #pragma unroll
        for (int j = 0; j < 4; ++j) acc[i][j] = zero;

    const int srow = tid >> 2;
    const int sk = (tid & 3) * 8;
    const unsigned short* gA0 = A + (size_t)(bm + srow) * K + sk;
    const unsigned short* gA1 = A + (size_t)(bm + 64 + srow) * K + sk;
    const unsigned short* gB0 = W + (size_t)(bn + srow) * K + sk;
    const unsigned short* gB1 = W + (size_t)(bn + 64 + srow) * K + sk;
    unsigned short* lA0 = As + (size_t)tid * 8;
    unsigned short* lA1 = As + (size_t)(256 + tid) * 8;
    unsigned short* lB0 = Bs + (size_t)tid * 8;
    unsigned short* lB1 = Bs + (size_t)(256 + tid) * 8;

    for (int k0 = 0; k0 < K; k0 += BK) {
        async_lds16(lA0, gA0 + k0);
        async_lds16(lA1, gA1 + k0);
        async_lds16(lB0, gB0 + k0);
        async_lds16(lB1, gB1 + k0);
        __syncthreads();
        short8 af[4], bfr[4];
        #pragma unroll
        for (int mi = 0; mi < 4; ++mi)
            af[mi] = *reinterpret_cast<const short8*>(&As[(wr * 64 + mi * 16 + lr) * BK + kg * 8]);
        #pragma unroll
        for (int ni = 0; ni < 4; ++ni)
            bfr[ni] = *reinterpret_cast<const short8*>(&Bs[(wc * 64 + ni * 16 + lr) * BK + kg * 8]);
        #pragma unroll
        for (int mi = 0; mi < 4; ++mi)
            #pragma unroll
            for (int ni = 0; ni < 4; ++ni)
                acc[mi][ni] = __builtin_amdgcn_mfma_f32_16x16x32_bf16(af[mi], bfr[ni], acc[mi][ni], 0, 0, 0);
        __syncthreads();
    }

    const int r0 = bm + wr * 64 + (lane >> 4) * 4;
    const int c0 = bn + wc * 64;
    #pragma unroll
    for (int mi = 0; mi < 4; ++mi) {
        #pragma unroll
        for (int ni = 0; ni < 4; ++ni) {
            const int col = c0 + ni * 16 + lr;
            #pragma unroll
            for (int j = 0; j < 4; ++j) {
                const int row = r0 + mi * 16 + j;
                float v = acc[mi][ni][j];
                if constexpr (EPI == 0) {
                    v += bias[col];
                    v = 1.0f / (1.0f + expf(-v));
                    outh[(size_t)row * N + col] = f2bf(v);
                } else if constexpr (EPI == 1) {
                    v += bias[col];
                    if (((col >> 6) % 3) == 0) v = 1.0f / (1.0f + expf(-v));
                    outh[(size_t)row * N + col] = f2bf(v);
                } else {
                    v += bias[col] + xres[(size_t)row * N + col];
                    outf[(size_t)row * N + col] = v;
                }
            }
        }
    }
}

// ---------------- selective scan (bf16 params in, bf16 ssm out) -------------
// ssm region must be pre-zeroed; we only write the live prefix.
__global__ __launch_bounds__(64) void scan_kernel(const unsigned short* __restrict__ pr,
                                                  const float* __restrict__ state,
                                                  unsigned short* __restrict__ ssm,
                                                  float* __restrict__ hlast) {
    const int bh = blockIdx.x;           // b*16 + h
    const int b = bh >> 4, h = bh & 15;
    const int s = threadIdx.x;           // 0..63
    const unsigned short* base = pr + (size_t)b * L * NP + h * 192 + s;
    unsigned short* ob = ssm + (size_t)b * L * D + h * 64 + s;
    const float h0 = state[(size_t)bh * 64 + s];
    float p = 1.0f, cu = 0.0f;
    bool live = true;
    for (int l = 0; l < L && live; l += 8) {
        float dv[8], bv[8], cv[8];
        #pragma unroll
        for (int j = 0; j < 8; ++j) {
            const unsigned short* pp = base + (size_t)(l + j) * NP;
            dv[j] = bf2f(pp[0]);
            bv[j] = bf2f(pp[64]);
            cv[j] = bf2f(pp[128]);
        }
        #pragma unroll
        for (int j = 0; j < 8; ++j) {
            p = p * dv[j];
            const float u = bv[j] / (p + 1e-8f);
            cu += u;
            const float hh = p * (h0 + cu);
            ob[(size_t)(l + j) * D] = f2bf(cv[j] * hh);
        }
        if (__all(p == 0.0f)) live = false;
    }
    hlast[(size_t)bh * 64 + s] = live ? p * (h0 + cu) : 0.0f;
}

// ---------------- mix: mixed = g*ssm + (1-g)*xn -> bf16 (in place over gate) --
__global__ __launch_bounds__(256) void mix_kernel(unsigned short* __restrict__ gate,
                                                  const unsigned short* __restrict__ ssm,
                                                  const unsigned short* __restrict__ xn) {
    const size_t i = ((size_t)blockIdx.x * 256 + threadIdx.x) * 4;
    const ushort4 g4 = *reinterpret_cast<const ushort4*>(gate + i);
    const ushort4 s4 = *reinterpret_cast<const ushort4*>(ssm + i);
    const ushort4 x4 = *reinterpret_cast<const ushort4*>(xn + i);
    ushort4 o;
    float g;
    g = bf2f(g4.x); o.x = f2bf(g * bf2f(s4.x) + (1.0f - g) * bf2f(x4.x));
    g = bf2f(g4.y); o.y = f2bf(g * bf2f(s4.y) + (1.0f - g) * bf2f(x4.y));
    g = bf2f(g4.z); o.z = f2bf(g * bf2f(s4.z) + (1.0f - g) * bf2f(x4.z));
    g = bf2f(g4.w); o.w = f2bf(g * bf2f(s4.w) + (1.0f - g) * bf2f(x4.w));
    *reinterpret_cast<ushort4*>(gate + i) = o;
}

extern "C" void kernel_launch(void* const* d_in, const int* in_sizes, int n_in,
                              void* d_out, int out_size, void* d_ws, size_t ws_size,
                              hipStream_t stream) {
    const float* x      = (const float*)d_in[0];
    const float* state  = (const float*)d_in[1];
    const float* norm_w = (const float*)d_in[2];
    const float* conv_w = (const float*)d_in[3];
    const float* conv_b = (const float*)d_in[4];
    const float* pw     = (const float*)d_in[5];
    const float* pb     = (const float*)d_in[6];
    const float* gw     = (const float*)d_in[7];
    const float* gb     = (const float*)d_in[8];
    const float* ow     = (const float*)d_in[9];
    const float* ob     = (const float*)d_in[10];

    // ws layout: gate 32MB | params 96MB | pwh 6MB | gwh 2MB | owh 2MB = 138MB
    constexpr size_t NEED = 138ull << 20;
    if (ws_size < NEED) return;  // fail loudly (absmax) instead of faulting

    char* ws = (char*)d_ws;
    unsigned short* gate  = (unsigned short*)(ws);                  // 32 MB (becomes mixed)
    unsigned short* mixed = gate;
    unsigned short* prm   = (unsigned short*)(ws + (32ull  << 20)); // 96 MB
    unsigned short* pwh   = (unsigned short*)(ws + (128ull << 20)); // 6 MB
    unsigned short* gwh   = (unsigned short*)(ws + (134ull << 20)); // 2 MB
    unsigned short* owh   = (unsigned short*)(ws + (136ull << 20)); // 2 MB

    // d_out doubles as scratch until the final GEMM overwrites it with y.
    float* y = (float*)d_out;
    float* hlast = y + (size_t)M * D;
    unsigned short* xn  = (unsigned short*)d_out;                   // bytes [0, 32MB)
    unsigned short* xc  = (unsigned short*)((char*)d_out + (32ull << 20)); // [32MB, 64MB)
    unsigned short* ssm = xc;                                       // reuses xc after GEMMs

    cvt_bf16_kernel<<<3072, 256, 0, stream>>>(pw, pwh, NP * 1024 / 4);
    cvt_bf16_kernel<<<1024, 256, 0, stream>>>(gw, gwh, 1024 * 1024 / 4);
    cvt_bf16_kernel<<<1024, 256, 0, stream>>>(ow, owh, 1024 * 1024 / 4);

    rmsnorm_kernel<<<M, 256, 0, stream>>>(x, norm_w, xn);
    conv_silu_kernel<<<M, 256, 0, stream>>>(xn, conv_w, conv_b, xc);

    gemm_bt_kernel<0><<<(M / 128) * (1024 / 128), 256, 0, stream>>>(xc, gwh, gb, nullptr, nullptr, gate, 1024);
    gemm_bt_kernel<1><<<(M / 128) * (NP / 128), 256, 0, stream>>>(xc, pwh, pb, nullptr, nullptr, prm, NP);

    // zero ssm region (32MB = 8192 blocks * 256 threads * 16B), then scan live prefix
    zfill_kernel<<<8192, 256, 0, stream>>>((uint4*)ssm);
    scan_kernel<<<NB * H, 64, 0, stream>>>(prm, state, ssm, hlast);

    mix_kernel<<<(M * D) / 1024, 256, 0, stream>>>(gate, ssm, xn);

    gemm_bt_kernel<2><<<(M / 128) * (1024 / 128), 256, 0, stream>>>(mixed, owh, ob, x, y, nullptr, 1024);
}

// Round 3
// 348.888 us; speedup vs baseline: 1.1516x; 1.1516x over previous
//
#include <hip/hip_runtime.h>
#include <stdint.h>

typedef __attribute__((ext_vector_type(8))) short short8;
typedef __attribute__((ext_vector_type(4))) float f32x4;

static constexpr int D  = 1024;
static constexpr int H  = 16;
static constexpr int L  = 4096;
static constexpr int NB = 4;
static constexpr int M  = NB * L;      // 16384 rows
static constexpr int NP = 3 * H * 64;  // 3072 param cols

__device__ __forceinline__ float bf2f(unsigned short u) {
    unsigned int v = ((unsigned int)u) << 16;
    return __builtin_bit_cast(float, v);
}
__device__ __forceinline__ unsigned short f2bf(float f) {
    unsigned int x = __builtin_bit_cast(unsigned int, f);
    x += 0x7fffu + ((x >> 16) & 1u);
    return (unsigned short)(x >> 16);
}
__device__ __forceinline__ void async_lds16(void* lds, const void* g) {
    __builtin_amdgcn_global_load_lds(
        (const __attribute__((address_space(1))) unsigned int*)g,
        (__attribute__((address_space(3))) unsigned int*)lds,
        16, 0, 0);
}

// ---------------- init: prefix[4] = 0 ----------------
__global__ void init_prefix_kernel(int* __restrict__ prefix) {
    if (threadIdx.x < NB) prefix[threadIdx.x] = 0;
}

// ---------------- plain fp32 -> bf16 cast ----------------
__global__ __launch_bounds__(256) void cvt_bf16_kernel(const float* __restrict__ src,
                                                       unsigned short* __restrict__ dst, int n4) {
    const int i = (blockIdx.x * 256 + threadIdx.x);
    if (i < n4) {
        const float4 v = reinterpret_cast<const float4*>(src)[i];
        ushort4 o;
        o.x = f2bf(v.x); o.y = f2bf(v.y); o.z = f2bf(v.z); o.w = f2bf(v.w);
        reinterpret_cast<ushort4*>(dst)[i] = o;
    }
}

// ---------------- gathered weight cast (one dst row per block) ----------------
// MODE 0: wgd rows 0..1023 = gw rows; rows 1024..2047 = pw delta rows (h*192+s)
// MODE 1: bc  rows 0..1023 = pw B rows (h*192+64+s); 1024..2047 = C rows (h*192+128+s)
template <int MODE>
__global__ __launch_bounds__(256) void gather_cvt_kernel(const float* __restrict__ gw,
                                                         const float* __restrict__ pw,
                                                         unsigned short* __restrict__ dst) {
    const int r = blockIdx.x;  // 0..2047
    const float* src;
    if (MODE == 0) {
        src = (r < 1024) ? (gw + (size_t)r * 1024)
                         : (pw + (size_t)(((r - 1024) >> 6) * 192 + ((r - 1024) & 63)) * 1024);
    } else {
        src = (r < 1024) ? (pw + (size_t)((r >> 6) * 192 + 64 + (r & 63)) * 1024)
                         : (pw + (size_t)(((r - 1024) >> 6) * 192 + 128 + ((r - 1024) & 63)) * 1024);
    }
    const int t = threadIdx.x * 4;
    const float4 v = *reinterpret_cast<const float4*>(src + t);
    ushort4 o;
    o.x = f2bf(v.x); o.y = f2bf(v.y); o.z = f2bf(v.z); o.w = f2bf(v.w);
    *reinterpret_cast<ushort4*>(dst + (size_t)r * 1024 + t) = o;
}

// ---------------- RMSNorm (fp32 in -> bf16 out) ----------------
__global__ __launch_bounds__(256) void rmsnorm_kernel(const float* __restrict__ x,
                                                      const float* __restrict__ w,
                                                      unsigned short* __restrict__ xn) {
    const int row = blockIdx.x;
    const int t = threadIdx.x;
    const float4 v = *reinterpret_cast<const float4*>(x + (size_t)row * D + t * 4);
    float s = v.x * v.x + v.y * v.y + v.z * v.z + v.w * v.w;
    #pragma unroll
    for (int o = 32; o > 0; o >>= 1) s += __shfl_down(s, o, 64);
    __shared__ float red[4];
    if ((t & 63) == 0) red[t >> 6] = s;
    __syncthreads();
    const float tot = red[0] + red[1] + red[2] + red[3];
    const float rinv = 1.0f / sqrtf(tot * (1.0f / D) + 1e-6f);
    const float4 wv = *reinterpret_cast<const float4*>(w + t * 4);
    ushort4 o;
    o.x = f2bf(wv.x * v.x * rinv);
    o.y = f2bf(wv.y * v.y * rinv);
    o.z = f2bf(wv.z * v.z * rinv);
    o.w = f2bf(wv.w * v.w * rinv);
    *reinterpret_cast<ushort4*>(xn + (size_t)row * D + t * 4) = o;
}

// ---------------- depthwise causal conv (K=4) + SiLU (bf16 -> bf16) --------
__global__ __launch_bounds__(256) void conv_silu_kernel(const unsigned short* __restrict__ xn,
                                                        const float* __restrict__ cw,
                                                        const float* __restrict__ cb,
                                                        unsigned short* __restrict__ xc) {
    const int row = blockIdx.x;          // b*L + l
    const int l = row & (L - 1);
    const int d0 = threadIdx.x * 4;
    float a[4];
    float wv[4][4];
    #pragma unroll
    for (int dd = 0; dd < 4; ++dd) {
        a[dd] = cb[d0 + dd];
        const float4 wr = *reinterpret_cast<const float4*>(cw + (size_t)(d0 + dd) * 4);
        wv[dd][0] = wr.x; wv[dd][1] = wr.y; wv[dd][2] = wr.z; wv[dd][3] = wr.w;
    }
    #pragma unroll
    for (int k = 0; k < 4; ++k) {
        if (l - 3 + k >= 0) {
            const ushort4 v = *reinterpret_cast<const ushort4*>(xn + (size_t)(row - 3 + k) * D + d0);
            a[0] += wv[0][k] * bf2f(v.x);
            a[1] += wv[1][k] * bf2f(v.y);
            a[2] += wv[2][k] * bf2f(v.z);
            a[3] += wv[3][k] * bf2f(v.w);
        }
    }
    ushort4 o;
    o.x = f2bf(a[0] / (1.0f + expf(-a[0])));
    o.y = f2bf(a[1] / (1.0f + expf(-a[1])));
    o.z = f2bf(a[2] / (1.0f + expf(-a[2])));
    o.w = f2bf(a[3] / (1.0f + expf(-a[3])));
    *reinterpret_cast<ushort4*>(xc + (size_t)row * D + d0) = o;
}

// ---------------- bf16 MFMA GEMM: out[m,n] = sum_k A[m,k]*W[n,k] + epilogue ----
// EPI 0 (N=2048): cols 0..1023 -> gate = sigmoid(v+gb) bf16; cols 1024.. -> delta
//                 = sigmoid(v+pb[idx]) into prm at h*192+s.
// EPI 1 (N=2048): B/C into prm (bias from pb); early-exit when row chunk >= prefix[b].
// EPI 2 (N=1024): y = v + bias + xres -> fp32
template <int EPI>
__global__ __launch_bounds__(256) void gemm_bt_kernel(
    const unsigned short* __restrict__ A,
    const unsigned short* __restrict__ W,
    const float* __restrict__ bias,
    const float* __restrict__ pb,
    const float* __restrict__ xres,
    float* __restrict__ outf,
    unsigned short* __restrict__ outh,
    unsigned short* __restrict__ prm,
    const int* __restrict__ prefix,
    const int N) {
    constexpr int K = 1024;
    constexpr int BK = 32;
    __shared__ alignas(16) unsigned short As[128 * BK];
    __shared__ alignas(16) unsigned short Bs[128 * BK];
    const int tid = threadIdx.x;
    const int wave = tid >> 6;
    const int lane = tid & 63;
    const int nbn = N >> 7;
    const int bm = (blockIdx.x / nbn) << 7;
    const int bn = (blockIdx.x % nbn) << 7;

    if constexpr (EPI == 1) {
        const int b = bm >> 12;
        if ((bm & (L - 1)) >= prefix[b]) return;  // block-uniform exit
    }

    const int wr = wave >> 1, wc = wave & 1;
    const int lr = lane & 15, kg = lane >> 4;

    f32x4 zero = {0.f, 0.f, 0.f, 0.f};
    f32x4 acc[4][4];
    #pragma unroll
    for (int i = 0; i < 4; ++i)
        #pragma unroll
        for (int j = 0; j < 4; ++j) acc[i][j] = zero;

    const int srow = tid >> 2;
    const int sk = (tid & 3) * 8;
    const unsigned short* gA0 = A + (size_t)(bm + srow) * K + sk;
    const unsigned short* gA1 = A + (size_t)(bm + 64 + srow) * K + sk;
    const unsigned short* gB0 = W + (size_t)(bn + srow) * K + sk;
    const unsigned short* gB1 = W + (size_t)(bn + 64 + srow) * K + sk;
    unsigned short* lA0 = As + (size_t)tid * 8;
    unsigned short* lA1 = As + (size_t)(256 + tid) * 8;
    unsigned short* lB0 = Bs + (size_t)tid * 8;
    unsigned short* lB1 = Bs + (size_t)(256 + tid) * 8;

    for (int k0 = 0; k0 < K; k0 += BK) {
        async_lds16(lA0, gA0 + k0);
        async_lds16(lA1, gA1 + k0);
        async_lds16(lB0, gB0 + k0);
        async_lds16(lB1, gB1 + k0);
        __syncthreads();
        short8 af[4], bfr[4];
        #pragma unroll
        for (int mi = 0; mi < 4; ++mi)
            af[mi] = *reinterpret_cast<const short8*>(&As[(wr * 64 + mi * 16 + lr) * BK + kg * 8]);
        #pragma unroll
        for (int ni = 0; ni < 4; ++ni)
            bfr[ni] = *reinterpret_cast<const short8*>(&Bs[(wc * 64 + ni * 16 + lr) * BK + kg * 8]);
        #pragma unroll
        for (int mi = 0; mi < 4; ++mi)
            #pragma unroll
            for (int ni = 0; ni < 4; ++ni)
                acc[mi][ni] = __builtin_amdgcn_mfma_f32_16x16x32_bf16(af[mi], bfr[ni], acc[mi][ni], 0, 0, 0);
        __syncthreads();
    }

    const int r0 = bm + wr * 64 + (lane >> 4) * 4;
    const int c0 = bn + wc * 64;
    #pragma unroll
    for (int mi = 0; mi < 4; ++mi) {
        #pragma unroll
        for (int ni = 0; ni < 4; ++ni) {
            const int col = c0 + ni * 16 + lr;
            #pragma unroll
            for (int j = 0; j < 4; ++j) {
                const int row = r0 + mi * 16 + j;
                float v = acc[mi][ni][j];
                if constexpr (EPI == 0) {
                    if (col < 1024) {
                        v += bias[col];
                        v = 1.0f / (1.0f + expf(-v));
                        outh[(size_t)row * 1024 + col] = f2bf(v);
                    } else {
                        const int c = col - 1024;
                        const int idx = (c >> 6) * 192 + (c & 63);
                        v += pb[idx];
                        v = 1.0f / (1.0f + expf(-v));
                        prm[(size_t)row * NP + idx] = f2bf(v);
                    }
                } else if constexpr (EPI == 1) {
                    int idx;
                    if (col < 1024) idx = (col >> 6) * 192 + 64 + (col & 63);
                    else { const int c = col - 1024; idx = (c >> 6) * 192 + 128 + (c & 63); }
                    v += pb[idx];
                    prm[(size_t)row * NP + idx] = f2bf(v);
                } else {
                    v += bias[col] + xres[(size_t)row * N + col];
                    outf[(size_t)row * N + col] = v;
                }
            }
        }
    }
}

// ---------------- prefix finder: delta cumprod saturation per batch ----------
__global__ __launch_bounds__(64) void prefix_kernel(const unsigned short* __restrict__ prm,
                                                    int* __restrict__ prefix) {
    const int bh = blockIdx.x;           // b*16 + h
    const int b = bh >> 4, h = bh & 15;
    const int s = threadIdx.x;
    const unsigned short* base = prm + (size_t)b * L * NP + h * 192 + s;
    float p = 1.0f;
    int lsat = L;
    for (int l = 0; l < L; l += 8) {
        float dv[8];
        #pragma unroll
        for (int j = 0; j < 8; ++j) dv[j] = bf2f(base[(size_t)(l + j) * NP]);
        #pragma unroll
        for (int j = 0; j < 8; ++j) p = p * dv[j];
        if (__all(p == 0.0f)) { lsat = l + 8; break; }
    }
    if (s == 0) atomicMax(prefix + b, lsat);
}

// ---------------- selective scan (bf16 params in, bf16 ssm out) -------------
// Writes ssm rows [0, l_sat); zero-fills [l_sat, prefix[b]) for this head.
__global__ __launch_bounds__(64) void scan_kernel(const unsigned short* __restrict__ prm,
                                                  const float* __restrict__ state,
                                                  unsigned short* __restrict__ ssm,
                                                  float* __restrict__ hlast,
                                                  const int* __restrict__ prefix) {
    const int bh = blockIdx.x;           // b*16 + h
    const int b = bh >> 4, h = bh & 15;
    const int s = threadIdx.x;           // 0..63
    const unsigned short* base = prm + (size_t)b * L * NP + h * 192 + s;
    unsigned short* ob = ssm + (size_t)b * L * D + h * 64 + s;
    const float h0 = state[(size_t)bh * 64 + s];
    float p = 1.0f, cu = 0.0f;
    bool live = true;
    int lend = 0;
    for (int l = 0; l < L && live; l += 8) {
        float dv[8], bv[8], cv[8];
        #pragma unroll
        for (int j = 0; j < 8; ++j) {
            const unsigned short* pp = base + (size_t)(l + j) * NP;
            dv[j] = bf2f(pp[0]);
            bv[j] = bf2f(pp[64]);
            cv[j] = bf2f(pp[128]);
        }
        #pragma unroll
        for (int j = 0; j < 8; ++j) {
            p = p * dv[j];
            const float u = bv[j] / (p + 1e-8f);
            cu += u;
            const float hh = p * (h0 + cu);
            ob[(size_t)(l + j) * D] = f2bf(cv[j] * hh);
        }
        lend = l + 8;
        if (__all(p == 0.0f)) live = false;
    }
    if (live) {
        hlast[(size_t)bh * 64 + s] = p * (h0 + cu);
    } else {
        hlast[(size_t)bh * 64 + s] = 0.0f;
        const int pf = prefix[b];
        for (int l = lend; l < pf; ++l) ob[(size_t)l * D] = 0;
    }
}

// ---------------- mix: mixed = g*ssm + (1-g)*xn -> bf16 (in place over gate) --
__global__ __launch_bounds__(256) void mix_kernel(unsigned short* __restrict__ gate,
                                                  const unsigned short* __restrict__ ssm,
                                                  const unsigned short* __restrict__ xn,
                                                  const int* __restrict__ prefix) {
    const size_t i = ((size_t)blockIdx.x * 256 + threadIdx.x) * 4;
    const int row = (int)(i >> 10);
    const int b = row >> 12;
    const int l = row & (L - 1);
    const ushort4 g4 = *reinterpret_cast<const ushort4*>(gate + i);
    const ushort4 x4 = *reinterpret_cast<const ushort4*>(xn + i);
    float sx = 0.f, sy = 0.f, sz = 0.f, sw = 0.f;
    if (l < prefix[b]) {
        const ushort4 s4 = *reinterpret_cast<const ushort4*>(ssm + i);
        sx = bf2f(s4.x); sy = bf2f(s4.y); sz = bf2f(s4.z); sw = bf2f(s4.w);
    }
    ushort4 o;
    float g;
    g = bf2f(g4.x); o.x = f2bf(g * sx + (1.0f - g) * bf2f(x4.x));
    g = bf2f(g4.y); o.y = f2bf(g * sy + (1.0f - g) * bf2f(x4.y));
    g = bf2f(g4.z); o.z = f2bf(g * sz + (1.0f - g) * bf2f(x4.z));
    g = bf2f(g4.w); o.w = f2bf(g * sw + (1.0f - g) * bf2f(x4.w));
    *reinterpret_cast<ushort4*>(gate + i) = o;
}

extern "C" void kernel_launch(void* const* d_in, const int* in_sizes, int n_in,
                              void* d_out, int out_size, void* d_ws, size_t ws_size,
                              hipStream_t stream) {
    const float* x      = (const float*)d_in[0];
    const float* state  = (const float*)d_in[1];
    const float* norm_w = (const float*)d_in[2];
    const float* conv_w = (const float*)d_in[3];
    const float* conv_b = (const float*)d_in[4];
    const float* pw     = (const float*)d_in[5];
    const float* pb     = (const float*)d_in[6];
    const float* gw     = (const float*)d_in[7];
    const float* gb     = (const float*)d_in[8];
    const float* ow     = (const float*)d_in[9];
    const float* ob     = (const float*)d_in[10];

    // ws: gate 32MB | prm 96MB | wgd 4MB (later owh) | bcwh 4MB | prefix 4KB
    constexpr size_t NEED = (136ull << 20) + 4096;
    if (ws_size < NEED) return;  // fail loudly instead of faulting

    char* ws = (char*)d_ws;
    unsigned short* gate  = (unsigned short*)(ws);                  // 32 MB (becomes mixed)
    unsigned short* mixed = gate;
    unsigned short* prm   = (unsigned short*)(ws + (32ull  << 20)); // 96 MB
    unsigned short* wgd   = (unsigned short*)(ws + (128ull << 20)); // 4 MB
    unsigned short* owh   = wgd;                                    // reuses wgd after GEMM0
    unsigned short* bcwh  = (unsigned short*)(ws + (132ull << 20)); // 4 MB
    int*            prefix = (int*)(ws + (136ull << 20));           // 16 B

    // d_out doubles as scratch until the final GEMM overwrites it with y.
    float* y = (float*)d_out;
    float* hlast = y + (size_t)M * D;
    unsigned short* xn  = (unsigned short*)d_out;                   // [0, 32MB)
    unsigned short* xc  = (unsigned short*)((char*)d_out + (32ull << 20)); // [32, 64MB)
    unsigned short* ssm = xc;  // scan overwrites xc region after B/C GEMM is done with it

    init_prefix_kernel<<<1, 64, 0, stream>>>(prefix);
    gather_cvt_kernel<0><<<2048, 256, 0, stream>>>(gw, pw, wgd);
    gather_cvt_kernel<1><<<2048, 256, 0, stream>>>(gw, pw, bcwh);

    rmsnorm_kernel<<<M, 256, 0, stream>>>(x, norm_w, xn);
    conv_silu_kernel<<<M, 256, 0, stream>>>(xn, conv_w, conv_b, xc);

    // GEMM0: gate + delta (N=2048)
    gemm_bt_kernel<0><<<(M / 128) * (2048 / 128), 256, 0, stream>>>(
        xc, wgd, gb, pb, nullptr, nullptr, gate, prm, nullptr, 2048);

    // ow cast into the now-dead wgd region
    cvt_bf16_kernel<<<1024, 256, 0, stream>>>(ow, owh, 1024 * 1024 / 4);

    prefix_kernel<<<NB * H, 64, 0, stream>>>(prm, prefix);

    // B/C GEMM, only live-prefix row blocks do work
    gemm_bt_kernel<1><<<(M / 128) * (2048 / 128), 256, 0, stream>>>(
        xc, bcwh, nullptr, pb, nullptr, nullptr, nullptr, prm, prefix, 2048);

    scan_kernel<<<NB * H, 64, 0, stream>>>(prm, state, ssm, hlast, prefix);

    mix_kernel<<<(M * D) / 1024, 256, 0, stream>>>(gate, ssm, xn, prefix);

    gemm_bt_kernel<2><<<(M / 128) * (1024 / 128), 256, 0, stream>>>(
        mixed, owh, ob, nullptr, x, y, nullptr, nullptr, nullptr, 1024);
}